// Round 4
// baseline (434.390 us; speedup 1.0000x reference)
//
#include <hip/hip_runtime.h>
#include <hip/hip_bf16.h>

typedef __bf16 bf16x8 __attribute__((ext_vector_type(8)));
typedef float f32x4 __attribute__((ext_vector_type(4)));
typedef float f32x16 __attribute__((ext_vector_type(16)));
typedef unsigned short u16;
typedef unsigned int u32;

// B=4, S=2048, D=1024, H=16, Dh=64
#define SB 4
#define SS 2048
#define SD 1024
#define SH 16
#define SDH 64

__device__ __forceinline__ u16 f2bf(float f) {
  union { float f; u32 u; } x; x.f = f;
  u32 r = (x.u + 0x7FFFu + ((x.u >> 16) & 1u)) >> 16;
  return (u16)r;
}

__device__ __forceinline__ void gl_lds16(const void* g, void* l) {
  __builtin_amdgcn_global_load_lds(
      (__attribute__((address_space(1))) void*)g,
      (__attribute__((address_space(3))) void*)l, 16, 0, 0);
}

// ---------------- cast fp32 -> bf16, 8 elems/thread ----------------
__global__ void cast_bf16_kernel(const float* __restrict__ in,
                                 u32* __restrict__ out, int n8) {
  int i = blockIdx.x * blockDim.x + threadIdx.x;
  if (i >= n8) return;
  const float4* inp = (const float4*)in;
  float4 a = inp[2 * i], b = inp[2 * i + 1];
  uint4 o;
  o.x = (u32)f2bf(a.x) | ((u32)f2bf(a.y) << 16);
  o.y = (u32)f2bf(a.z) | ((u32)f2bf(a.w) << 16);
  o.z = (u32)f2bf(b.x) | ((u32)f2bf(b.y) << 16);
  o.w = (u32)f2bf(b.z) | ((u32)f2bf(b.w) << 16);
  ((uint4*)out)[i] = o;
}

// ---------------- transpose + cast weight: Wt[n][k] = W[k][n] ------
__global__ void transpose_cast_kernel(const float* __restrict__ W,
                                      u16* __restrict__ Wt) {
  __shared__ float t[32][33];
  int bx = blockIdx.x, by = blockIdx.y;
  int tx = threadIdx.x, ty = threadIdx.y;  // 32 x 8
#pragma unroll
  for (int j = 0; j < 32; j += 8)
    t[ty + j][tx] = W[(size_t)(by * 32 + ty + j) * SD + bx * 32 + tx];
  __syncthreads();
#pragma unroll
  for (int j = 0; j < 32; j += 8)
    Wt[(size_t)(bx * 32 + ty + j) * SD + by * 32 + tx] = f2bf(t[tx][ty + j]);
}

// ---------------- GEMM: C[m][n] = sum_k A[m][k]*Bt[n][k] (+bias) ---
// 128x128 tile, BK=64, double-buffered counted staging,
// T2 XOR swizzle on LDS (byte ^= (row&7)<<4, pre-swizzled gl_lds source).
// MODE 0: out bf16 Qh[b][h][s][dh], scale log2e/8 (bias[n])
// MODE 1: out bf16 Kh[b][h][s][dh]               (bias[n])
// MODE 2: out bf16 Vt[b][h][dh][s]  (A=WvT M=1024, Bt=vb N=8192, bias[m])
// MODE 3: out fp32 [m][n] (+bias[n])
template <int MODE>
__global__ __launch_bounds__(256, 2)
void gemm_bt(const u16* __restrict__ A, const u16* __restrict__ Bt,
             const float* __restrict__ bias, void* __restrict__ Out,
             int M, int N, int K) {
  __shared__ u16 Asl[2][128 * 64];
  __shared__ u16 Bsl[2][128 * 64];
  const int ntile = N >> 7;
  int bid = blockIdx.x;
  bid = (bid & 7) * ((int)gridDim.x >> 3) + (bid >> 3);  // XCD chunk swizzle
  int m0 = (bid / ntile) * 128, n0 = (bid % ntile) * 128;
  int tid = threadIdx.x;
  int lane = tid & 63, wv = tid >> 6;
  int wr = wv >> 1, wc = wv & 1;

  auto stage = [&](int buf, int k0) {
#pragma unroll
    for (int it = 0; it < 4; ++it) {
      int c = tid + it * 256;            // 1024 chunks of 16B per matrix
      int row = c >> 3, sl = c & 7;      // 8 x 16B per 128B row
      int ssl = sl ^ (row & 7);          // pre-swizzled source slot
      gl_lds16(A + (size_t)(m0 + row) * K + k0 + ssl * 8,
               (char*)&Asl[buf][0] + c * 16);
      gl_lds16(Bt + (size_t)(n0 + row) * K + k0 + ssl * 8,
               (char*)&Bsl[buf][0] + c * 16);
    }
  };

  f32x4 acc[4][4] = {};
  stage(0, 0);
  asm volatile("s_waitcnt vmcnt(0)" ::: "memory");
  __syncthreads();

  int nk = K >> 6;
  for (int kt = 0; kt < nk; ++kt) {
    int buf = kt & 1;
    if (kt + 1 < nk) stage(buf ^ 1, (kt + 1) << 6);
#pragma unroll
    for (int kk = 0; kk < 2; ++kk) {
      bf16x8 af[4], bfr[4];
#pragma unroll
      for (int i = 0; i < 4; ++i) {
        int ar = wr * 64 + i * 16 + (lane & 15);
        int abyt = (ar * 128 + (kk * 32 + (lane >> 4) * 8) * 2) ^
                   ((ar & 7) << 4);
        af[i] = *(const bf16x8*)((const char*)&Asl[buf][0] + abyt);
        int br = wc * 64 + i * 16 + (lane & 15);
        int bbyt = (br * 128 + (kk * 32 + (lane >> 4) * 8) * 2) ^
                   ((br & 7) << 4);
        bfr[i] = *(const bf16x8*)((const char*)&Bsl[buf][0] + bbyt);
      }
#pragma unroll
      for (int i = 0; i < 4; ++i)
#pragma unroll
        for (int j = 0; j < 4; ++j)
          acc[i][j] = __builtin_amdgcn_mfma_f32_16x16x32_bf16(
              af[i], bfr[j], acc[i][j], 0, 0, 0);
    }
    asm volatile("s_waitcnt vmcnt(0)" ::: "memory");
    __syncthreads();
  }

  int cg = lane >> 4, cc = lane & 15;
#pragma unroll
  for (int i = 0; i < 4; ++i) {
#pragma unroll
    for (int j = 0; j < 4; ++j) {
#pragma unroll
      for (int r = 0; r < 4; ++r) {
        int m = m0 + wr * 64 + i * 16 + cg * 4 + r;
        int n = n0 + wc * 64 + j * 16 + cc;
        float val = acc[i][j][r];
        if (MODE == 0) {
          // fold (1/sqrt(Dh)) * log2(e) into Q for exp2-based softmax
          val = (val + bias[n]) * 0.18033688011112042f;
          int b = m >> 11, s = m & 2047, h = n >> 6, dh = n & 63;
          ((u16*)Out)[((size_t)((b * SH + h) * SS + s) << 6) + dh] = f2bf(val);
        } else if (MODE == 1) {
          val += bias[n];
          int b = m >> 11, s = m & 2047, h = n >> 6, dh = n & 63;
          ((u16*)Out)[((size_t)((b * SH + h) * SS + s) << 6) + dh] = f2bf(val);
        } else if (MODE == 2) {
          val += bias[m];  // m is the 1024-dim here
          int h = m >> 6, dh = m & 63, b = n >> 11, s = n & 2047;
          ((u16*)Out)[((size_t)((b * SH + h) * SDH + dh) << 11) + s] = f2bf(val);
        } else {
          val += bias[n];
          ((float*)Out)[(size_t)m * N + n] = val;
        }
      }
    }
  }
}

// ---------------- attention (no-LDS, swapped-QK^T, 32x32x16) ------------
// K/V per (b,h) = 512KB -> L2-resident on its XCD (swizzle co-locates all
// 8 q-tile blocks of a bh). Fragments loaded global->register directly in
// MFMA layout; zero barriers in the main loop; unroll-2 register double
// buffer for the next 64-key tile. Softmax fully in-register (exp2 with
// log2(w) C-in init, cvt_pk + permlane32_swap for P->bf16 A-frags).
__global__ __launch_bounds__(256, 2)
void attn_kernel(const u16* __restrict__ Qh, const u16* __restrict__ Kh,
                 const u16* __restrict__ Vt, const float* __restrict__ w,
                 u16* __restrict__ Ctx) {
  __shared__ float wl[SS];  // log2(w) for this batch row

  int bid = blockIdx.x;
  int swz = (bid & 7) * 64 + (bid >> 3);  // XCD chunk swizzle (512 = 8*64)
  int bh = swz >> 3;                      // 0..63
  int qt = swz & 7;                       // 0..7
  int b = bh >> 4, hh = bh & 15;
  int q0 = qt * 256;
  int tid = threadIdx.x, lane = tid & 63, wv = tid >> 6;
  int ql = lane & 31, h = lane >> 5;
  const size_t basebh = (size_t)bh * (SS * SDH);
  const u16* Kb = Kh + basebh + (size_t)ql * SDH + h * 8;
  const u16* Vb = Vt + basebh + (size_t)ql * SS + h * 8;

  // Q fragments (B-operand): q-block u covers cols q0+wv*64+u*32+ql
  bf16x8 qf[2][4];
#pragma unroll
  for (int u = 0; u < 2; ++u) {
    const u16* qp =
        Qh + basebh + (size_t)(q0 + wv * 64 + u * 32 + ql) * SDH + h * 8;
#pragma unroll
    for (int st = 0; st < 4; ++st) qf[u][st] = *(const bf16x8*)(qp + st * 16);
  }

  auto loadK = [&](bf16x8 (&kf)[2][4], int t) {
    const u16* p = Kb + (size_t)t * 64 * SDH;
#pragma unroll
    for (int kt = 0; kt < 2; ++kt)
#pragma unroll
      for (int st = 0; st < 4; ++st)
        kf[kt][st] = *(const bf16x8*)(p + kt * 32 * SDH + st * 16);
  };
  auto loadV = [&](bf16x8 (&vf)[4][2], int t) {
    const u16* p = Vb + t * 64;
#pragma unroll
    for (int ksl = 0; ksl < 4; ++ksl)
#pragma unroll
      for (int vr = 0; vr < 2; ++vr)
        vf[ksl][vr] = *(const bf16x8*)(p + (size_t)vr * 32 * SS + ksl * 16);
  };

  f32x16 ctx[2][2] = {};
  float rs[2] = {0.f, 0.f};

  auto compute = [&](const bf16x8 (&kf)[2][4], const bf16x8 (&vf)[4][2],
                     int t) {
    int kvb = t * 64;
#pragma unroll
    for (int kt = 0; kt < 2; ++kt) {
      float4 lw[4];
#pragma unroll
      for (int e2 = 0; e2 < 4; ++e2)
        lw[e2] = *(const float4*)&wl[kvb + kt * 32 + e2 * 8 + h * 4];
      u32 pk[2][4][2];
#pragma unroll
      for (int u = 0; u < 2; ++u) {
        f32x16 sc;
#pragma unroll
        for (int e2 = 0; e2 < 4; ++e2) {
          sc[e2 * 4 + 0] = lw[e2].x;
          sc[e2 * 4 + 1] = lw[e2].y;
          sc[e2 * 4 + 2] = lw[e2].z;
          sc[e2 * 4 + 3] = lw[e2].w;
        }
        __builtin_amdgcn_s_setprio(1);
#pragma unroll
        for (int st = 0; st < 4; ++st)
          sc = __builtin_amdgcn_mfma_f32_32x32x16_bf16(kf[kt][st], qf[u][st],
                                                       sc, 0, 0, 0);
        __builtin_amdgcn_s_setprio(0);
        // lane: P[q=ql][k = kvb + 32kt + (reg&3) + 8*(reg>>2) + 4h]
#pragma unroll
        for (int e2 = 0; e2 < 4; ++e2) {
          float v0 = __builtin_amdgcn_exp2f(sc[e2 * 4 + 0]);
          float v1 = __builtin_amdgcn_exp2f(sc[e2 * 4 + 1]);
          float v2 = __builtin_amdgcn_exp2f(sc[e2 * 4 + 2]);
          float v3 = __builtin_amdgcn_exp2f(sc[e2 * 4 + 3]);
          rs[u] += (v0 + v1) + (v2 + v3);
          u32 p0, p1;
          asm("v_cvt_pk_bf16_f32 %0, %1, %2" : "=v"(p0) : "v"(v0), "v"(v1));
          asm("v_cvt_pk_bf16_f32 %0, %1, %2" : "=v"(p1) : "v"(v2), "v"(v3));
          pk[u][e2][0] = p0;
          pk[u][e2][1] = p1;
        }
      }
      // PV for the two 16-key slices of this kt (ksl = kt*2 + ksl2)
#pragma unroll
      for (int ksl2 = 0; ksl2 < 2; ++ksl2) {
        int ksl = kt * 2 + ksl2;
#pragma unroll
        for (int u = 0; u < 2; ++u) {
          u32 d0 = pk[u][2 * ksl2][0], d1 = pk[u][2 * ksl2][1];
          u32 s0 = pk[u][2 * ksl2 + 1][0], s1 = pk[u][2 * ksl2 + 1][1];
          asm("v_permlane32_swap_b32 %0, %1" : "+v"(d0), "+v"(s0));
          asm("v_permlane32_swap_b32 %0, %1" : "+v"(d1), "+v"(s1));
          union { u32 uu[4]; bf16x8 v; } pa;
          pa.uu[0] = d0; pa.uu[1] = d1; pa.uu[2] = s0; pa.uu[3] = s1;
          __builtin_amdgcn_s_setprio(1);
          ctx[u][0] = __builtin_amdgcn_mfma_f32_32x32x16_bf16(
              pa.v, vf[ksl][0], ctx[u][0], 0, 0, 0);
          ctx[u][1] = __builtin_amdgcn_mfma_f32_32x32x16_bf16(
              pa.v, vf[ksl][1], ctx[u][1], 0, 0, 0);
          __builtin_amdgcn_s_setprio(0);
        }
      }
    }
  };

  bf16x8 kA[2][4], vA[4][2], kB[2][4], vB[4][2];
  loadK(kA, 0);
  loadV(vA, 0);

  // fill log2(w) table (only LDS use; single barrier)
  const float* wb = w + b * SS;
  for (int i = tid; i < SS; i += 256)
    wl[i] = __builtin_amdgcn_logf(wb[i]);  // v_log_f32 = log2
  __syncthreads();

  for (int t = 0; t < 32; t += 2) {
    loadK(kB, t + 1);
    loadV(vB, t + 1);
    compute(kA, vA, t);
    if (t + 2 < 32) {
      loadK(kA, t + 2);
      loadV(vA, t + 2);
    }
    compute(kB, vB, t + 1);
  }

  // denominator + context write
#pragma unroll
  for (int u = 0; u < 2; ++u) {
    float rsu = rs[u];
    rsu += __shfl_xor(rsu, 32, 64);
    float rinv = 1.0f / (rsu + 1e-12f);
#pragma unroll
    for (int reg = 0; reg < 16; ++reg) {
      int qrow = (reg & 3) + 8 * (reg >> 2) + 4 * h;
      float ri = __shfl(rinv, qrow, 64);
      int srow = q0 + wv * 64 + u * 32 + qrow;
      size_t base = ((size_t)(b * SS + srow) << 10) + hh * SDH;
      Ctx[base + ql] = f2bf(ctx[u][0][reg] * ri);
      Ctx[base + 32 + ql] = f2bf(ctx[u][1][reg] * ri);
    }
  }
}

extern "C" void kernel_launch(void* const* d_in, const int* in_sizes, int n_in,
                              void* d_out, int out_size, void* d_ws,
                              size_t ws_size, hipStream_t stream) {
  const float* q = (const float*)d_in[0];
  const float* k = (const float*)d_in[1];
  const float* v = (const float*)d_in[2];
  const float* w = (const float*)d_in[3];
  const float* Wq = (const float*)d_in[4];
  const float* bq = (const float*)d_in[5];
  const float* Wk = (const float*)d_in[6];
  const float* bk = (const float*)d_in[7];
  const float* Wv = (const float*)d_in[8];
  const float* bv = (const float*)d_in[9];
  const float* Wo = (const float*)d_in[10];
  const float* bo = (const float*)d_in[11];
  float* out = (float*)d_out;

  char* ws = (char*)d_ws;
  const size_t SZ = (size_t)8192 * 1024 * 2;  // one bf16 [8192][1024] buffer
  u16* qb = (u16*)(ws);
  u16* kb = (u16*)(ws + SZ);
  u16* vb = (u16*)(ws + 2 * SZ);
  u16* WqT = (u16*)(ws + 3 * SZ);
  u16* WkT = WqT + 1024 * 1024;
  u16* WvT = WkT + 1024 * 1024;
  u16* WoT = WvT + 1024 * 1024;
  u16* Qh = (u16*)(ws + 3 * SZ + (size_t)4 * 1024 * 1024 * 2);
  u16* Kh = Qh + (size_t)8192 * 1024;
  u16* Vt = Kh + (size_t)8192 * 1024;
  u16* Ctx = qb;  // qb is dead after the Q projection

  // 1) casts (8192*1024 elems each, 8 per thread)
  cast_bf16_kernel<<<4096, 256, 0, stream>>>(q, (u32*)qb, 1048576);
  cast_bf16_kernel<<<4096, 256, 0, stream>>>(k, (u32*)kb, 1048576);
  cast_bf16_kernel<<<4096, 256, 0, stream>>>(v, (u32*)vb, 1048576);

  // 2) weight transposes
  dim3 tb(32, 8), tg(32, 32);
  transpose_cast_kernel<<<tg, tb, 0, stream>>>(Wq, WqT);
  transpose_cast_kernel<<<tg, tb, 0, stream>>>(Wk, WkT);
  transpose_cast_kernel<<<tg, tb, 0, stream>>>(Wv, WvT);
  transpose_cast_kernel<<<tg, tb, 0, stream>>>(Wo, WoT);

  // 3) projections
  gemm_bt<0><<<512, 256, 0, stream>>>(qb, WqT, bq, Qh, 8192, 1024, 1024);
  gemm_bt<1><<<512, 256, 0, stream>>>(kb, WkT, bk, Kh, 8192, 1024, 1024);
  gemm_bt<2><<<512, 256, 0, stream>>>(WvT, vb, bv, Vt, 1024, 8192, 1024);

  // 4) attention
  attn_kernel<<<512, 256, 0, stream>>>(Qh, Kh, Vt, w, Ctx);

  // 5) output projection (fp32 out + bias)
  gemm_bt<3><<<512, 256, 0, stream>>>(Ctx, WoT, bo, out, 8192, 1024, 1024);
}

// Round 5
// 367.507 us; speedup vs baseline: 1.1820x; 1.1820x over previous
//
#include <hip/hip_runtime.h>
#include <hip/hip_bf16.h>

typedef __bf16 bf16x8 __attribute__((ext_vector_type(8)));
typedef float f32x4 __attribute__((ext_vector_type(4)));
typedef float f32x16 __attribute__((ext_vector_type(16)));
typedef unsigned short u16;
typedef unsigned int u32;

// B=4, S=2048, D=1024, H=16, Dh=64
#define SB 4
#define SS 2048
#define SD 1024
#define SH 16
#define SDH 64

__device__ __forceinline__ u16 f2bf(float f) {
  union { float f; u32 u; } x; x.f = f;
  u32 r = (x.u + 0x7FFFu + ((x.u >> 16) & 1u)) >> 16;
  return (u16)r;
}

__device__ __forceinline__ void gl_lds16(const void* g, void* l) {
  __builtin_amdgcn_global_load_lds(
      (__attribute__((address_space(1))) void*)g,
      (__attribute__((address_space(3))) void*)l, 16, 0, 0);
}

// ---------------- transpose + cast weight: Wt[n][k] = W[k][n] ------
__global__ void transpose_cast_kernel(const float* __restrict__ W,
                                      u16* __restrict__ Wt) {
  __shared__ float t[32][33];
  int bx = blockIdx.x, by = blockIdx.y;
  int tx = threadIdx.x, ty = threadIdx.y;  // 32 x 8
#pragma unroll
  for (int j = 0; j < 32; j += 8)
    t[ty + j][tx] = W[(size_t)(by * 32 + ty + j) * SD + bx * 32 + tx];
  __syncthreads();
#pragma unroll
  for (int j = 0; j < 32; j += 8)
    Wt[(size_t)(bx * 32 + ty + j) * SD + by * 32 + tx] = f2bf(t[tx][ty + j]);
}

// ---------------- GEMM: C[m][n] = sum_k A[m][k]*Bt[n][k] (+bias) ---
// 128x128 tile, BK=64, double-buffered, T2 XOR swizzle on LDS.
// fp32 operands are cast-fused: load f32 -> regs early (T14 issue-early),
// cvt_pk + swizzled ds_write after compute (write-late). bf16 operands go
// via global_load_lds with pre-swizzled source.
// MODE 0: A=q f32, out bf16 Qh[b][h][s][dh], scale log2e/8 (bias[n])
// MODE 1: A=k f32, out bf16 Kh[b][h][s][dh]                (bias[n])
// MODE 2: A=WvT bf16, B=v f32, out bf16 Vt[b][h][dh][s], bias[m]
// MODE 3: both bf16, out fp32 [m][n] (+bias[n])
template <int MODE>
__global__ __launch_bounds__(256, 2)
void gemm_bt(const void* __restrict__ Ap, const void* __restrict__ Btp,
             const float* __restrict__ bias, void* __restrict__ Out,
             int M, int N, int K) {
  constexpr bool CA = (MODE == 0 || MODE == 1);  // A is fp32 (cast-fused)
  constexpr bool CB = (MODE == 2);               // B is fp32 (cast-fused)
  __shared__ u16 Asl[2][128 * 64];
  __shared__ u16 Bsl[2][128 * 64];
  const u16* Ab = (const u16*)Ap;
  const float* Af = (const float*)Ap;
  const u16* Bb = (const u16*)Btp;
  const float* Bf = (const float*)Btp;

  const int ntile = N >> 7;
  int bid = blockIdx.x;
  bid = (bid & 7) * ((int)gridDim.x >> 3) + (bid >> 3);  // XCD chunk swizzle
  int m0 = (bid / ntile) * 128, n0 = (bid % ntile) * 128;
  int tid = threadIdx.x;
  int lane = tid & 63, wv = tid >> 6;
  int wr = wv >> 1, wc = wv & 1;

  float4 regA[4][2], regB[4][2];

  // issue global loads for the fp32 operand(s) of tile k0 (kept in regs)
  auto load_cast = [&](int k0) {
#pragma unroll
    for (int it = 0; it < 4; ++it) {
      int c = tid + it * 256;
      int row = c >> 3, sl = c & 7;
      if (CA) {
        const float* s = Af + (size_t)(m0 + row) * K + k0 + sl * 8;
        regA[it][0] = *(const float4*)s;
        regA[it][1] = *(const float4*)(s + 4);
      }
      if (CB) {
        const float* s = Bf + (size_t)(n0 + row) * K + k0 + sl * 8;
        regB[it][0] = *(const float4*)s;
        regB[it][1] = *(const float4*)(s + 4);
      }
    }
  };
  // issue gl_lds for the bf16 operand(s)
  auto stage_lds = [&](int buf, int k0) {
#pragma unroll
    for (int it = 0; it < 4; ++it) {
      int c = tid + it * 256;
      int row = c >> 3, sl = c & 7;
      int ssl = sl ^ (row & 7);
      if (!CA)
        gl_lds16(Ab + (size_t)(m0 + row) * K + k0 + ssl * 8,
                 (char*)&Asl[buf][0] + c * 16);
      if (!CB)
        gl_lds16(Bb + (size_t)(n0 + row) * K + k0 + ssl * 8,
                 (char*)&Bsl[buf][0] + c * 16);
    }
  };
  // cvt + swizzled LDS write of the reg-staged fp32 operand(s)
  auto write_cast = [&](int buf) {
#pragma unroll
    for (int it = 0; it < 4; ++it) {
      int c = tid + it * 256;
      int row = c >> 3, sl = c & 7;
      int dst = (row * 128 + sl * 16) ^ ((row & 7) << 4);
      if (CA) {
        uint4 o;
        asm("v_cvt_pk_bf16_f32 %0, %1, %2"
            : "=v"(o.x) : "v"(regA[it][0].x), "v"(regA[it][0].y));
        asm("v_cvt_pk_bf16_f32 %0, %1, %2"
            : "=v"(o.y) : "v"(regA[it][0].z), "v"(regA[it][0].w));
        asm("v_cvt_pk_bf16_f32 %0, %1, %2"
            : "=v"(o.z) : "v"(regA[it][1].x), "v"(regA[it][1].y));
        asm("v_cvt_pk_bf16_f32 %0, %1, %2"
            : "=v"(o.w) : "v"(regA[it][1].z), "v"(regA[it][1].w));
        *(uint4*)((char*)&Asl[buf][0] + dst) = o;
      }
      if (CB) {
        uint4 o;
        asm("v_cvt_pk_bf16_f32 %0, %1, %2"
            : "=v"(o.x) : "v"(regB[it][0].x), "v"(regB[it][0].y));
        asm("v_cvt_pk_bf16_f32 %0, %1, %2"
            : "=v"(o.y) : "v"(regB[it][0].z), "v"(regB[it][0].w));
        asm("v_cvt_pk_bf16_f32 %0, %1, %2"
            : "=v"(o.z) : "v"(regB[it][1].x), "v"(regB[it][1].y));
        asm("v_cvt_pk_bf16_f32 %0, %1, %2"
            : "=v"(o.w) : "v"(regB[it][1].z), "v"(regB[it][1].w));
        *(uint4*)((char*)&Bsl[buf][0] + dst) = o;
      }
    }
  };

  f32x4 acc[4][4] = {};
  load_cast(0);
  stage_lds(0, 0);
  write_cast(0);
  asm volatile("s_waitcnt vmcnt(0)" ::: "memory");
  __syncthreads();

  int nk = K >> 6;
  for (int kt = 0; kt < nk; ++kt) {
    int buf = kt & 1;
    if (kt + 1 < nk) {
      load_cast((kt + 1) << 6);
      stage_lds(buf ^ 1, (kt + 1) << 6);
    }
#pragma unroll
    for (int kk = 0; kk < 2; ++kk) {
      bf16x8 af[4], bfr[4];
#pragma unroll
      for (int i = 0; i < 4; ++i) {
        int ar = wr * 64 + i * 16 + (lane & 15);
        int abyt = (ar * 128 + (kk * 32 + (lane >> 4) * 8) * 2) ^
                   ((ar & 7) << 4);
        af[i] = *(const bf16x8*)((const char*)&Asl[buf][0] + abyt);
        int br = wc * 64 + i * 16 + (lane & 15);
        int bbyt = (br * 128 + (kk * 32 + (lane >> 4) * 8) * 2) ^
                   ((br & 7) << 4);
        bfr[i] = *(const bf16x8*)((const char*)&Bsl[buf][0] + bbyt);
      }
#pragma unroll
      for (int i = 0; i < 4; ++i)
#pragma unroll
        for (int j = 0; j < 4; ++j)
          acc[i][j] = __builtin_amdgcn_mfma_f32_16x16x32_bf16(
              af[i], bfr[j], acc[i][j], 0, 0, 0);
    }
    if (kt + 1 < nk) write_cast(buf ^ 1);
    asm volatile("s_waitcnt vmcnt(0)" ::: "memory");
    __syncthreads();
  }

  int cg = lane >> 4, cc = lane & 15;
#pragma unroll
  for (int i = 0; i < 4; ++i) {
#pragma unroll
    for (int j = 0; j < 4; ++j) {
#pragma unroll
      for (int r = 0; r < 4; ++r) {
        int m = m0 + wr * 64 + i * 16 + cg * 4 + r;
        int n = n0 + wc * 64 + j * 16 + cc;
        float val = acc[i][j][r];
        if (MODE == 0) {
          // fold (1/sqrt(Dh)) * log2(e) into Q for exp2-based softmax
          val = (val + bias[n]) * 0.18033688011112042f;
          int b = m >> 11, s = m & 2047, h = n >> 6, dh = n & 63;
          ((u16*)Out)[((size_t)((b * SH + h) * SS + s) << 6) + dh] = f2bf(val);
        } else if (MODE == 1) {
          val += bias[n];
          int b = m >> 11, s = m & 2047, h = n >> 6, dh = n & 63;
          ((u16*)Out)[((size_t)((b * SH + h) * SS + s) << 6) + dh] = f2bf(val);
        } else if (MODE == 2) {
          val += bias[m];  // m is the 1024-dim here
          int h = m >> 6, dh = m & 63, b = n >> 11, s = n & 2047;
          ((u16*)Out)[((size_t)((b * SH + h) * SDH + dh) << 11) + s] = f2bf(val);
        } else {
          val += bias[n];
          ((float*)Out)[(size_t)m * N + n] = val;
        }
      }
    }
  }
}

// ---------------- attention (no-LDS K/V, swapped-QK^T, 32x32x16) --------
// K/V per (b,h) = 512KB -> L2-resident (XCD swizzle co-locates the 8
// q-tile blocks of a bh). Fragments load global->register in MFMA layout.
// Register budget controlled (R4 lesson): K ping-pong (kA/kB), V single
// buffer, V-loads issued before the exp/cvt phase so latency hides there.
// Live ~= kA32+kB32+vf32+qf32+ctx64+pk16+sc16+misc ~ 246 < 256.
__global__ __launch_bounds__(256, 2)
void attn_kernel(const u16* __restrict__ Qh, const u16* __restrict__ Kh,
                 const u16* __restrict__ Vt, const float* __restrict__ w,
                 u16* __restrict__ Ctx) {
  __shared__ float wl[SS];  // log2(w) for this batch row

  int bid = blockIdx.x;
  int swz = (bid & 7) * 64 + (bid >> 3);  // XCD chunk swizzle (512 = 8*64)
  int bh = swz >> 3;                      // 0..63
  int qt = swz & 7;                       // 0..7
  int b = bh >> 4, hh = bh & 15;
  int q0 = qt * 256;
  int tid = threadIdx.x, lane = tid & 63, wv = tid >> 6;
  int ql = lane & 31, h = lane >> 5;
  const size_t basebh = (size_t)bh * (SS * SDH);
  const u16* Kb = Kh + basebh + (size_t)ql * SDH + h * 8;
  const u16* Vb = Vt + basebh + (size_t)ql * SS + h * 8;

  // Q fragments (B-operand): q-block u covers cols q0+wv*64+u*32+ql
  bf16x8 qf[2][4];
#pragma unroll
  for (int u = 0; u < 2; ++u) {
    const u16* qp =
        Qh + basebh + (size_t)(q0 + wv * 64 + u * 32 + ql) * SDH + h * 8;
#pragma unroll
    for (int st = 0; st < 4; ++st) qf[u][st] = *(const bf16x8*)(qp + st * 16);
  }

  bf16x8 kA[2][4], kB[2][4], vf[4][2];
  auto loadK = [&](bf16x8 (&kf)[2][4], int t) {
    const u16* p = Kb + (size_t)t * 64 * SDH;
#pragma unroll
    for (int kt = 0; kt < 2; ++kt)
#pragma unroll
      for (int st = 0; st < 4; ++st)
        kf[kt][st] = *(const bf16x8*)(p + kt * 32 * SDH + st * 16);
  };
  auto loadV = [&](int t) {
    const u16* p = Vb + t * 64;
#pragma unroll
    for (int ksl = 0; ksl < 4; ++ksl)
#pragma unroll
      for (int vr = 0; vr < 2; ++vr)
        vf[ksl][vr] = *(const bf16x8*)(p + (size_t)vr * 32 * SS + ksl * 16);
  };

  f32x16 ctx[2][2] = {};
  float rs[2] = {0.f, 0.f};

  auto compute = [&](const bf16x8 (&kf)[2][4], int t) {
    int kvb = t * 64;
    u32 pk[2][8][2];
#pragma unroll
    for (int kt = 0; kt < 2; ++kt) {
      float4 lw[4];
#pragma unroll
      for (int e2 = 0; e2 < 4; ++e2)
        lw[e2] = *(const float4*)&wl[kvb + kt * 32 + e2 * 8 + h * 4];
#pragma unroll
      for (int u = 0; u < 2; ++u) {
        f32x16 sc;
#pragma unroll
        for (int e2 = 0; e2 < 4; ++e2) {
          sc[e2 * 4 + 0] = lw[e2].x;
          sc[e2 * 4 + 1] = lw[e2].y;
          sc[e2 * 4 + 2] = lw[e2].z;
          sc[e2 * 4 + 3] = lw[e2].w;
        }
        __builtin_amdgcn_s_setprio(1);
#pragma unroll
        for (int st = 0; st < 4; ++st)
          sc = __builtin_amdgcn_mfma_f32_32x32x16_bf16(kf[kt][st], qf[u][st],
                                                       sc, 0, 0, 0);
        __builtin_amdgcn_s_setprio(0);
        // lane: P[q=ql][k = kvb + 32kt + (reg&3) + 8*(reg>>2) + 4h]
#pragma unroll
        for (int e2 = 0; e2 < 4; ++e2) {
          float v0 = __builtin_amdgcn_exp2f(sc[e2 * 4 + 0]);
          float v1 = __builtin_amdgcn_exp2f(sc[e2 * 4 + 1]);
          float v2 = __builtin_amdgcn_exp2f(sc[e2 * 4 + 2]);
          float v3 = __builtin_amdgcn_exp2f(sc[e2 * 4 + 3]);
          rs[u] += (v0 + v1) + (v2 + v3);
          u32 p0, p1;
          asm("v_cvt_pk_bf16_f32 %0, %1, %2" : "=v"(p0) : "v"(v0), "v"(v1));
          asm("v_cvt_pk_bf16_f32 %0, %1, %2" : "=v"(p1) : "v"(v2), "v"(v3));
          pk[u][kt * 4 + e2][0] = p0;
          pk[u][kt * 4 + e2][1] = p1;
        }
      }
    }
    // PV (vf must have landed; loads were issued before compute)
#pragma unroll
    for (int ksl = 0; ksl < 4; ++ksl) {
#pragma unroll
      for (int u = 0; u < 2; ++u) {
        u32 d0 = pk[u][2 * ksl][0], d1 = pk[u][2 * ksl][1];
        u32 s0 = pk[u][2 * ksl + 1][0], s1 = pk[u][2 * ksl + 1][1];
        asm("v_permlane32_swap_b32 %0, %1" : "+v"(d0), "+v"(s0));
        asm("v_permlane32_swap_b32 %0, %1" : "+v"(d1), "+v"(s1));
        union { u32 uu[4]; bf16x8 v; } pa;
        pa.uu[0] = d0; pa.uu[1] = d1; pa.uu[2] = s0; pa.uu[3] = s1;
        __builtin_amdgcn_s_setprio(1);
        ctx[u][0] = __builtin_amdgcn_mfma_f32_32x32x16_bf16(
            pa.v, vf[ksl][0], ctx[u][0], 0, 0, 0);
        ctx[u][1] = __builtin_amdgcn_mfma_f32_32x32x16_bf16(
            pa.v, vf[ksl][1], ctx[u][1], 0, 0, 0);
        __builtin_amdgcn_s_setprio(0);
      }
    }
  };

  loadK(kA, 0);

  // fill log2(w) table (only LDS use; single barrier)
  const float* wb = w + b * SS;
  for (int i = tid; i < SS; i += 256)
    wl[i] = __builtin_amdgcn_logf(wb[i]);  // v_log_f32 = log2
  __syncthreads();

  for (int t = 0; t < 32; t += 2) {
    loadK(kB, t + 1);
    loadV(t);
    compute(kA, t);
    if (t + 2 < 32) loadK(kA, t + 2);
    loadV(t + 1);
    compute(kB, t + 1);
  }

  // denominator + context write
#pragma unroll
  for (int u = 0; u < 2; ++u) {
    float rsu = rs[u];
    rsu += __shfl_xor(rsu, 32, 64);
    float rinv = 1.0f / (rsu + 1e-12f);
#pragma unroll
    for (int reg = 0; reg < 16; ++reg) {
      int qrow = (reg & 3) + 8 * (reg >> 2) + 4 * h;
      float ri = __shfl(rinv, qrow, 64);
      int srow = q0 + wv * 64 + u * 32 + qrow;
      size_t base = ((size_t)(b * SS + srow) << 10) + hh * SDH;
      Ctx[base + ql] = f2bf(ctx[u][0][reg] * ri);
      Ctx[base + 32 + ql] = f2bf(ctx[u][1][reg] * ri);
    }
  }
}

extern "C" void kernel_launch(void* const* d_in, const int* in_sizes, int n_in,
                              void* d_out, int out_size, void* d_ws,
                              size_t ws_size, hipStream_t stream) {
  const float* q = (const float*)d_in[0];
  const float* k = (const float*)d_in[1];
  const float* v = (const float*)d_in[2];
  const float* w = (const float*)d_in[3];
  const float* Wq = (const float*)d_in[4];
  const float* bq = (const float*)d_in[5];
  const float* Wk = (const float*)d_in[6];
  const float* bk = (const float*)d_in[7];
  const float* Wv = (const float*)d_in[8];
  const float* bv = (const float*)d_in[9];
  const float* Wo = (const float*)d_in[10];
  const float* bo = (const float*)d_in[11];
  float* out = (float*)d_out;

  char* ws = (char*)d_ws;
  const size_t SZ = (size_t)8192 * 1024 * 2;  // one bf16 [8192][1024] buffer
  u16* Ctx = (u16*)(ws);
  u16* WqT = (u16*)(ws + 3 * SZ);
  u16* WkT = WqT + 1024 * 1024;
  u16* WvT = WkT + 1024 * 1024;
  u16* WoT = WvT + 1024 * 1024;
  u16* Qh = (u16*)(ws + 3 * SZ + (size_t)4 * 1024 * 1024 * 2);
  u16* Kh = Qh + (size_t)8192 * 1024;
  u16* Vt = Kh + (size_t)8192 * 1024;

  // 1) weight transposes (tiny)
  dim3 tb(32, 8), tg(32, 32);
  transpose_cast_kernel<<<tg, tb, 0, stream>>>(Wq, WqT);
  transpose_cast_kernel<<<tg, tb, 0, stream>>>(Wk, WkT);
  transpose_cast_kernel<<<tg, tb, 0, stream>>>(Wv, WvT);
  transpose_cast_kernel<<<tg, tb, 0, stream>>>(Wo, WoT);

  // 2) projections (fp32 inputs cast-fused into staging)
  gemm_bt<0><<<512, 256, 0, stream>>>(q, WqT, bq, Qh, 8192, 1024, 1024);
  gemm_bt<1><<<512, 256, 0, stream>>>(k, WkT, bk, Kh, 8192, 1024, 1024);
  gemm_bt<2><<<512, 256, 0, stream>>>(WvT, v, bv, Vt, 1024, 8192, 1024);

  // 3) attention
  attn_kernel<<<512, 256, 0, stream>>>(Qh, Kh, Vt, w, Ctx);

  // 4) output projection (fp32 out + bias)
  gemm_bt<3><<<512, 256, 0, stream>>>(Ctx, WoT, bo, out, 8192, 1024, 1024);
}

// Round 6
// 223.586 us; speedup vs baseline: 1.9428x; 1.6437x over previous
//
#include <hip/hip_runtime.h>
#include <hip/hip_bf16.h>

typedef __bf16 bf16x8 __attribute__((ext_vector_type(8)));
typedef float f32x4 __attribute__((ext_vector_type(4)));
typedef float f32x16 __attribute__((ext_vector_type(16)));
typedef unsigned short u16;
typedef unsigned int u32;

// B=4, S=2048, D=1024, H=16, Dh=64
#define SB 4
#define SS 2048
#define SD 1024
#define SH 16
#define SDH 64

__device__ __forceinline__ u16 f2bf(float f) {
  union { float f; u32 u; } x; x.f = f;
  u32 r = (x.u + 0x7FFFu + ((x.u >> 16) & 1u)) >> 16;
  return (u16)r;
}

__device__ __forceinline__ void gl_lds16(const void* g, void* l) {
  __builtin_amdgcn_global_load_lds(
      (__attribute__((address_space(1))) void*)g,
      (__attribute__((address_space(3))) void*)l, 16, 0, 0);
}

// ---------------- log2(w) precompute (8192 elems) ------------------
__global__ void log2w_kernel(const float* __restrict__ w,
                             float* __restrict__ lwg) {
  int i = blockIdx.x * 256 + threadIdx.x;
  lwg[i] = __builtin_amdgcn_logf(w[i]);  // v_log_f32 = log2
}

// ---------------- transpose + cast 4 weights: Wt[n][k] = W[k][n] ---
__global__ void transpose_cast_kernel(const float* __restrict__ W0,
                                      const float* __restrict__ W1,
                                      const float* __restrict__ W2,
                                      const float* __restrict__ W3,
                                      u16* __restrict__ T0,
                                      u16* __restrict__ T1,
                                      u16* __restrict__ T2,
                                      u16* __restrict__ T3) {
  __shared__ float t[32][33];
  int z = blockIdx.z;
  const float* W = (z == 0) ? W0 : (z == 1) ? W1 : (z == 2) ? W2 : W3;
  u16* Wt = (z == 0) ? T0 : (z == 1) ? T1 : (z == 2) ? T2 : T3;
  int bx = blockIdx.x, by = blockIdx.y;
  int tx = threadIdx.x, ty = threadIdx.y;  // 32 x 8
#pragma unroll
  for (int j = 0; j < 32; j += 8)
    t[ty + j][tx] = W[(size_t)(by * 32 + ty + j) * SD + bx * 32 + tx];
  __syncthreads();
#pragma unroll
  for (int j = 0; j < 32; j += 8)
    Wt[(size_t)(bx * 32 + ty + j) * SD + by * 32 + tx] = f2bf(t[tx][ty + j]);
}

// ---------------- GEMM: C[m][n] = sum_k A[m][k]*Bt[n][k] (+bias) ---
// 128x128 tile, BK=64, double-buffered; counted vmcnt (no drains), raw
// barriers (2/K-step). fp32 operands cast-fused (reg-stage + cvt + swizzled
// ds_write); bf16 operands via linear-dest gl_lds with pre-swizzled source.
// MODE 0: A=q f32 -> Qh[b][h][s][dh] bf16 row-major, scale log2e/8, bias[n]
// MODE 1: A=k f32 -> Kf fragment-major (QK A-operand frags), bias[n]
// MODE 2: A=WvT bf16, B=v f32 -> Vf fragment-major (PV B-operand), bias[m]
// MODE 3: both bf16 -> fp32 [m][n] + bias[n]
template <int MODE>
__global__ __launch_bounds__(256, 2)
void gemm_bt(const void* __restrict__ Ap, const void* __restrict__ Btp,
             const float* __restrict__ bias, void* __restrict__ Out,
             int M, int N, int K) {
  constexpr bool CA = (MODE == 0 || MODE == 1);  // A is fp32 (cast-fused)
  constexpr bool CB = (MODE == 2);               // B is fp32 (cast-fused)
  __shared__ u16 Asl[2][128 * 64];
  __shared__ u16 Bsl[2][128 * 64];
  const u16* Ab = (const u16*)Ap;
  const float* Af = (const float*)Ap;
  const u16* Bb = (const u16*)Btp;
  const float* Bf = (const float*)Btp;

  const int ntile = N >> 7;
  int bid = blockIdx.x;
  bid = (bid & 7) * ((int)gridDim.x >> 3) + (bid >> 3);  // XCD chunk swizzle
  int m0 = (bid / ntile) * 128, n0 = (bid % ntile) * 128;
  int tid = threadIdx.x;
  int lane = tid & 63, wv = tid >> 6;
  int wr = wv >> 1, wc = wv & 1;

  float4 regA[4][2], regB[4][2];

  auto load_cast = [&](int k0) {
#pragma unroll
    for (int it = 0; it < 4; ++it) {
      int c = tid + it * 256;
      int row = c >> 3, sl = c & 7;
      if (CA) {
        const float* s = Af + (size_t)(m0 + row) * K + k0 + sl * 8;
        regA[it][0] = *(const float4*)s;
        regA[it][1] = *(const float4*)(s + 4);
      }
      if (CB) {
        const float* s = Bf + (size_t)(n0 + row) * K + k0 + sl * 8;
        regB[it][0] = *(const float4*)s;
        regB[it][1] = *(const float4*)(s + 4);
      }
    }
  };
  auto stage_lds = [&](int buf, int k0) {
#pragma unroll
    for (int it = 0; it < 4; ++it) {
      int c = tid + it * 256;
      int row = c >> 3, sl = c & 7;
      int ssl = sl ^ (row & 7);
      if (!CA)
        gl_lds16(Ab + (size_t)(m0 + row) * K + k0 + ssl * 8,
                 (char*)&Asl[buf][0] + c * 16);
      if (!CB)
        gl_lds16(Bb + (size_t)(n0 + row) * K + k0 + ssl * 8,
                 (char*)&Bsl[buf][0] + c * 16);
    }
  };
  auto write_cast = [&](int buf) {
#pragma unroll
    for (int it = 0; it < 4; ++it) {
      int c = tid + it * 256;
      int row = c >> 3, sl = c & 7;
      int dst = (row * 128 + sl * 16) ^ ((row & 7) << 4);
      if (CA) {
        uint4 o;
        asm("v_cvt_pk_bf16_f32 %0, %1, %2"
            : "=v"(o.x) : "v"(regA[it][0].x), "v"(regA[it][0].y));
        asm("v_cvt_pk_bf16_f32 %0, %1, %2"
            : "=v"(o.y) : "v"(regA[it][0].z), "v"(regA[it][0].w));
        asm("v_cvt_pk_bf16_f32 %0, %1, %2"
            : "=v"(o.z) : "v"(regA[it][1].x), "v"(regA[it][1].y));
        asm("v_cvt_pk_bf16_f32 %0, %1, %2"
            : "=v"(o.w) : "v"(regA[it][1].z), "v"(regA[it][1].w));
        *(uint4*)((char*)&Asl[buf][0] + dst) = o;
      }
      if (CB) {
        uint4 o;
        asm("v_cvt_pk_bf16_f32 %0, %1, %2"
            : "=v"(o.x) : "v"(regB[it][0].x), "v"(regB[it][0].y));
        asm("v_cvt_pk_bf16_f32 %0, %1, %2"
            : "=v"(o.y) : "v"(regB[it][0].z), "v"(regB[it][0].w));
        asm("v_cvt_pk_bf16_f32 %0, %1, %2"
            : "=v"(o.z) : "v"(regB[it][1].x), "v"(regB[it][1].y));
        asm("v_cvt_pk_bf16_f32 %0, %1, %2"
            : "=v"(o.w) : "v"(regB[it][1].z), "v"(regB[it][1].w));
        *(uint4*)((char*)&Bsl[buf][0] + dst) = o;
      }
    }
  };

  f32x4 acc[4][4] = {};
  load_cast(0);
  stage_lds(0, 0);
  write_cast(0);

  int nk = K >> 6;
  for (int kt = 0; kt < nk; ++kt) {
    int buf = kt & 1;
    if (kt + 1 < nk) {
      load_cast((kt + 1) << 6);
      stage_lds(buf ^ 1, (kt + 1) << 6);
      if (CA || CB)
        asm volatile("s_waitcnt vmcnt(12) lgkmcnt(0)" ::: "memory");
      else
        asm volatile("s_waitcnt vmcnt(8) lgkmcnt(0)" ::: "memory");
    } else {
      asm volatile("s_waitcnt vmcnt(0) lgkmcnt(0)" ::: "memory");
    }
    __builtin_amdgcn_s_barrier();  // cur tile ready in LDS
#pragma unroll
    for (int kk = 0; kk < 2; ++kk) {
      bf16x8 af[4], bfr[4];
#pragma unroll
      for (int i = 0; i < 4; ++i) {
        int ar = wr * 64 + i * 16 + (lane & 15);
        int abyt = (ar * 128 + (kk * 32 + (lane >> 4) * 8) * 2) ^
                   ((ar & 7) << 4);
        af[i] = *(const bf16x8*)((const char*)&Asl[buf][0] + abyt);
        int br = wc * 64 + i * 16 + (lane & 15);
        int bbyt = (br * 128 + (kk * 32 + (lane >> 4) * 8) * 2) ^
                   ((br & 7) << 4);
        bfr[i] = *(const bf16x8*)((const char*)&Bsl[buf][0] + bbyt);
      }
#pragma unroll
      for (int i = 0; i < 4; ++i)
#pragma unroll
        for (int j = 0; j < 4; ++j)
          acc[i][j] = __builtin_amdgcn_mfma_f32_16x16x32_bf16(
              af[i], bfr[j], acc[i][j], 0, 0, 0);
    }
    if (kt + 1 < nk) write_cast(buf ^ 1);
    __builtin_amdgcn_s_barrier();  // all waves done reading cur tile
  }

  int cg = lane >> 4, cc = lane & 15;
#pragma unroll
  for (int i = 0; i < 4; ++i) {
#pragma unroll
    for (int j = 0; j < 4; ++j) {
#pragma unroll
      for (int r = 0; r < 4; ++r) {
        int m = m0 + wr * 64 + i * 16 + cg * 4 + r;
        int n = n0 + wc * 64 + j * 16 + cc;
        float val = acc[i][j][r];
        if (MODE == 0) {
          // fold (1/sqrt(Dh)) * log2(e) into Q for exp2-based softmax
          val = (val + bias[n]) * 0.18033688011112042f;
          int b = m >> 11, s = m & 2047, h = n >> 6, dh = n & 63;
          ((u16*)Out)[((size_t)((b * SH + h) * SS + s) << 6) + dh] = f2bf(val);
        } else if (MODE == 1) {
          // Kf fragment-major: frag(kb32=s>>5, st=dh>>4), lane=(s&31)+((dh>>3)&1)*32, j=dh&7
          val += bias[n];
          int b = m >> 11, s = m & 2047, h = n >> 6, dh = n & 63;
          size_t off = ((size_t)(b * SH + h) << 17) + ((size_t)(s >> 5) << 11) +
                       ((size_t)(dh >> 4) << 9) +
                       ((size_t)((s & 31) | ((dh & 8) << 2)) << 3) + (dh & 7);
          ((u16*)Out)[off] = f2bf(val);
        } else if (MODE == 2) {
          // Vf fragment-major: frag(kb16=s>>4, dhh=dh>>5), lane=((s>>3)&1)*32+(dh&31), j=s&7
          val += bias[m];  // m is the 1024-dim here
          int h = m >> 6, dh = m & 63, b = n >> 11, s = n & 2047;
          size_t off = ((size_t)(b * SH + h) << 17) + ((size_t)(s >> 4) << 10) +
                       ((size_t)(dh >> 5) << 9) +
                       ((size_t)(((s >> 3) & 1) * 32 + (dh & 31)) << 3) +
                       (s & 7);
          ((u16*)Out)[off] = f2bf(val);
        } else {
          val += bias[n];
          ((float*)Out)[(size_t)m * N + n] = val;
        }
      }
    }
  }
}

// ---------------- attention (frag-major LDS, ring-3, counted vmcnt) -----
// grid 512 = 64 bh x 8 q-tiles of 256 rows; 4 waves x 64 q-rows (u=2).
// K/V staged as contiguous 1KB fragments -> linear gl_lds, lane*16
// ds_read_b128: ZERO bank conflicts. Ring-3 buffers, one raw barrier and
// vmcnt(4) per 64-key tile (stage t+2 in flight across barriers).
__global__ __launch_bounds__(256, 2)
void attn_kernel(const u16* __restrict__ Qh, const u16* __restrict__ Kf,
                 const u16* __restrict__ Vf, const float* __restrict__ lwg,
                 u16* __restrict__ Ctx) {
  __shared__ u16 Kl[3][4096];  // 8KB per 64-key tile (16 x 1KB frags)
  __shared__ u16 Vl[3][4096];

  int bid = blockIdx.x;
  int swz = (bid & 7) * 64 + (bid >> 3);  // XCD chunk swizzle (512 = 8*64)
  int bh = swz >> 3;                      // 0..63
  int qt = swz & 7;                       // 0..7
  int b = bh >> 4, hh = bh & 15;
  int q0 = qt * 256;
  int tid = threadIdx.x, lane = tid & 63, wv = tid >> 6;
  int ql = lane & 31, h = lane >> 5;
  const size_t basebh = (size_t)bh * (SS * SDH);
  const char* Ksrc = (const char*)(Kf + basebh);
  const char* Vsrc = (const char*)(Vf + basebh);
  const float* lwp = lwg + b * SS;

  // Q fragments (B-operand): q-block u covers cols q0+wv*64+u*32+ql
  bf16x8 qf[2][4];
#pragma unroll
  for (int u = 0; u < 2; ++u) {
    const u16* qp =
        Qh + basebh + (size_t)(q0 + wv * 64 + u * 32 + ql) * SDH + h * 8;
#pragma unroll
    for (int st = 0; st < 4; ++st) qf[u][st] = *(const bf16x8*)(qp + st * 16);
  }

  auto stage = [&](int s, int t) {
#pragma unroll
    for (int it = 0; it < 2; ++it) {
      int c = tid + it * 256;  // 512 chunks of 16B = 8KB, fully linear
      gl_lds16(Ksrc + (size_t)t * 8192 + c * 16, (char*)&Kl[s][0] + c * 16);
      gl_lds16(Vsrc + (size_t)t * 8192 + c * 16, (char*)&Vl[s][0] + c * 16);
    }
  };

  f32x16 ctx[2][2] = {};
  float rs[2] = {0.f, 0.f};

  auto compute = [&](const char* Ks, const char* Vs, int t) {
    int kvb = t * 64;
    u32 pk[2][8][2];
#pragma unroll
    for (int kt = 0; kt < 2; ++kt) {
      bf16x8 kf[4];
#pragma unroll
      for (int st = 0; st < 4; ++st)
        kf[st] = *(const bf16x8*)(Ks + (kt * 4 + st) * 1024 + lane * 16);
      float4 lw[4];
#pragma unroll
      for (int e2 = 0; e2 < 4; ++e2)
        lw[e2] = *(const float4*)(lwp + kvb + kt * 32 + e2 * 8 + h * 4);
#pragma unroll
      for (int u = 0; u < 2; ++u) {
        f32x16 sc;
#pragma unroll
        for (int e2 = 0; e2 < 4; ++e2) {
          sc[e2 * 4 + 0] = lw[e2].x;
          sc[e2 * 4 + 1] = lw[e2].y;
          sc[e2 * 4 + 2] = lw[e2].z;
          sc[e2 * 4 + 3] = lw[e2].w;
        }
        __builtin_amdgcn_s_setprio(1);
#pragma unroll
        for (int st = 0; st < 4; ++st)
          sc = __builtin_amdgcn_mfma_f32_32x32x16_bf16(kf[st], qf[u][st], sc,
                                                       0, 0, 0);
        __builtin_amdgcn_s_setprio(0);
        // lane: P[q=ql][k = kvb + 32kt + (reg&3) + 8*(reg>>2) + 4h]
#pragma unroll
        for (int e2 = 0; e2 < 4; ++e2) {
          float v0 = __builtin_amdgcn_exp2f(sc[e2 * 4 + 0]);
          float v1 = __builtin_amdgcn_exp2f(sc[e2 * 4 + 1]);
          float v2 = __builtin_amdgcn_exp2f(sc[e2 * 4 + 2]);
          float v3 = __builtin_amdgcn_exp2f(sc[e2 * 4 + 3]);
          rs[u] += (v0 + v1) + (v2 + v3);
          u32 p0, p1;
          asm("v_cvt_pk_bf16_f32 %0, %1, %2" : "=v"(p0) : "v"(v0), "v"(v1));
          asm("v_cvt_pk_bf16_f32 %0, %1, %2" : "=v"(p1) : "v"(v2), "v"(v3));
          pk[u][kt * 4 + e2][0] = p0;
          pk[u][kt * 4 + e2][1] = p1;
        }
      }
    }
    // PV over four 16-key slices; V frags are lane-contiguous (no conflicts)
#pragma unroll
    for (int ksl = 0; ksl < 4; ++ksl) {
      bf16x8 vf0 = *(const bf16x8*)(Vs + (ksl * 2 + 0) * 1024 + lane * 16);
      bf16x8 vf1 = *(const bf16x8*)(Vs + (ksl * 2 + 1) * 1024 + lane * 16);
#pragma unroll
      for (int u = 0; u < 2; ++u) {
        u32 d0 = pk[u][2 * ksl][0], d1 = pk[u][2 * ksl][1];
        u32 s0 = pk[u][2 * ksl + 1][0], s1 = pk[u][2 * ksl + 1][1];
        asm("v_permlane32_swap_b32 %0, %1" : "+v"(d0), "+v"(s0));
        asm("v_permlane32_swap_b32 %0, %1" : "+v"(d1), "+v"(s1));
        union { u32 uu[4]; bf16x8 v; } pa;
        pa.uu[0] = d0; pa.uu[1] = d1; pa.uu[2] = s0; pa.uu[3] = s1;
        __builtin_amdgcn_s_setprio(1);
        ctx[u][0] = __builtin_amdgcn_mfma_f32_32x32x16_bf16(pa.v, vf0,
                                                            ctx[u][0], 0, 0, 0);
        ctx[u][1] = __builtin_amdgcn_mfma_f32_32x32x16_bf16(pa.v, vf1,
                                                            ctx[u][1], 0, 0, 0);
        __builtin_amdgcn_s_setprio(0);
      }
    }
  };

  stage(0, 0);
  stage(1, 1);

  for (int t = 0; t < 32; ++t) {
    if (t < 31)
      asm volatile("s_waitcnt vmcnt(4)" ::: "memory");
    else
      asm volatile("s_waitcnt vmcnt(0)" ::: "memory");
    __builtin_amdgcn_s_barrier();  // tile t ready; all waves done with t-1
    if (t + 2 < 32) stage((t + 2) % 3, t + 2);
    int s = t % 3;
    compute((const char*)&Kl[s][0], (const char*)&Vl[s][0], t);
  }

  // denominator + context write
#pragma unroll
  for (int u = 0; u < 2; ++u) {
    float rsu = rs[u];
    rsu += __shfl_xor(rsu, 32, 64);
    float rinv = 1.0f / (rsu + 1e-12f);
#pragma unroll
    for (int reg = 0; reg < 16; ++reg) {
      int qrow = (reg & 3) + 8 * (reg >> 2) + 4 * h;
      float ri = __shfl(rinv, qrow, 64);
      int srow = q0 + wv * 64 + u * 32 + qrow;
      size_t base = ((size_t)(b * SS + srow) << 10) + hh * SDH;
      Ctx[base + ql] = f2bf(ctx[u][0][reg] * ri);
      Ctx[base + 32 + ql] = f2bf(ctx[u][1][reg] * ri);
    }
  }
}

extern "C" void kernel_launch(void* const* d_in, const int* in_sizes, int n_in,
                              void* d_out, int out_size, void* d_ws,
                              size_t ws_size, hipStream_t stream) {
  const float* q = (const float*)d_in[0];
  const float* k = (const float*)d_in[1];
  const float* v = (const float*)d_in[2];
  const float* w = (const float*)d_in[3];
  const float* Wq = (const float*)d_in[4];
  const float* bq = (const float*)d_in[5];
  const float* Wk = (const float*)d_in[6];
  const float* bk = (const float*)d_in[7];
  const float* Wv = (const float*)d_in[8];
  const float* bv = (const float*)d_in[9];
  const float* Wo = (const float*)d_in[10];
  const float* bo = (const float*)d_in[11];
  float* out = (float*)d_out;

  char* ws = (char*)d_ws;
  const size_t SZ = (size_t)8192 * 1024 * 2;  // one bf16 [8192][1024] buffer
  u16* Ctx = (u16*)(ws);
  u16* WqT = (u16*)(ws + 3 * SZ);
  u16* WkT = WqT + 1024 * 1024;
  u16* WvT = WkT + 1024 * 1024;
  u16* WoT = WvT + 1024 * 1024;
  u16* Qh = (u16*)(ws + 3 * SZ + (size_t)4 * 1024 * 1024 * 2);
  u16* Kf = Qh + (size_t)8192 * 1024;
  u16* Vf = Kf + (size_t)8192 * 1024;
  float* lwg = (float*)(ws + 3 * SZ + (size_t)4 * 1024 * 1024 * 2 +
                        (size_t)3 * 8192 * 1024 * 2);

  // 1) tiny precomputes
  log2w_kernel<<<32, 256, 0, stream>>>(w, lwg);
  dim3 tb(32, 8), tg(32, 32, 4);
  transpose_cast_kernel<<<tg, tb, 0, stream>>>(Wq, Wk, Wv, Wo,
                                               WqT, WkT, WvT, WoT);

  // 2) projections (fp32 inputs cast-fused into staging)
  gemm_bt<0><<<512, 256, 0, stream>>>(q, WqT, bq, Qh, 8192, 1024, 1024);
  gemm_bt<1><<<512, 256, 0, stream>>>(k, WkT, bk, Kf, 8192, 1024, 1024);
  gemm_bt<2><<<512, 256, 0, stream>>>(WvT, v, bv, Vf, 1024, 8192, 1024);

  // 3) attention
  attn_kernel<<<512, 256, 0, stream>>>(Qh, Kf, Vf, lwg, Ctx);

  // 4) output projection (fp32 out + bias)
  gemm_bt<3><<<512, 256, 0, stream>>>(Ctx, WoT, bo, out, 8192, 1024, 1024);
}

// Round 7
// 210.176 us; speedup vs baseline: 2.0668x; 1.0638x over previous
//
#include <hip/hip_runtime.h>
#include <hip/hip_bf16.h>

typedef __bf16 bf16x8 __attribute__((ext_vector_type(8)));
typedef float f32x4 __attribute__((ext_vector_type(4)));
typedef float f32x16 __attribute__((ext_vector_type(16)));
typedef unsigned short u16;
typedef unsigned int u32;

// B=4, S=2048, D=1024, H=16, Dh=64
#define SB 4
#define SS 2048
#define SD 1024
#define SH 16
#define SDH 64

__device__ __forceinline__ u16 f2bf(float f) {
  union { float f; u32 u; } x; x.f = f;
  u32 r = (x.u + 0x7FFFu + ((x.u >> 16) & 1u)) >> 16;
  return (u16)r;
}

__device__ __forceinline__ void gl_lds16(const void* g, void* l) {
  __builtin_amdgcn_global_load_lds(
      (__attribute__((address_space(1))) void*)g,
      (__attribute__((address_space(3))) void*)l, 16, 0, 0);
}

// ---------------- cast fp32 -> bf16, 8 elems/thread ----------------
__global__ void cast_bf16_kernel(const float* __restrict__ in,
                                 u32* __restrict__ out, int n8) {
  int i = blockIdx.x * blockDim.x + threadIdx.x;
  if (i >= n8) return;
  const float4* inp = (const float4*)in;
  float4 a = inp[2 * i], b = inp[2 * i + 1];
  uint4 o;
  asm("v_cvt_pk_bf16_f32 %0, %1, %2" : "=v"(o.x) : "v"(a.x), "v"(a.y));
  asm("v_cvt_pk_bf16_f32 %0, %1, %2" : "=v"(o.y) : "v"(a.z), "v"(a.w));
  asm("v_cvt_pk_bf16_f32 %0, %1, %2" : "=v"(o.z) : "v"(b.x), "v"(b.y));
  asm("v_cvt_pk_bf16_f32 %0, %1, %2" : "=v"(o.w) : "v"(b.z), "v"(b.w));
  ((uint4*)out)[i] = o;
}

// ---------------- log2(w) precompute (8192 elems) ------------------
__global__ void log2w_kernel(const float* __restrict__ w,
                             float* __restrict__ lwg) {
  int i = blockIdx.x * 256 + threadIdx.x;
  lwg[i] = __builtin_amdgcn_logf(w[i]);  // v_log_f32 = log2
}

// ---------------- transpose + cast 4 weights: Wt[n][k] = W[k][n] ---
__global__ void transpose_cast_kernel(const float* __restrict__ W0,
                                      const float* __restrict__ W1,
                                      const float* __restrict__ W2,
                                      const float* __restrict__ W3,
                                      u16* __restrict__ T0,
                                      u16* __restrict__ T1,
                                      u16* __restrict__ T2,
                                      u16* __restrict__ T3) {
  __shared__ float t[32][33];
  int z = blockIdx.z;
  const float* W = (z == 0) ? W0 : (z == 1) ? W1 : (z == 2) ? W2 : W3;
  u16* Wt = (z == 0) ? T0 : (z == 1) ? T1 : (z == 2) ? T2 : T3;
  int bx = blockIdx.x, by = blockIdx.y;
  int tx = threadIdx.x, ty = threadIdx.y;  // 32 x 8
#pragma unroll
  for (int j = 0; j < 32; j += 8)
    t[ty + j][tx] = W[(size_t)(by * 32 + ty + j) * SD + bx * 32 + tx];
  __syncthreads();
#pragma unroll
  for (int j = 0; j < 32; j += 8)
    Wt[(size_t)(bx * 32 + ty + j) * SD + by * 32 + tx] = f2bf(t[tx][ty + j]);
}

// ---------------- GEMM: C[m][n] = sum_k A[m][k]*Bt[n][k] (+bias) ---
// 128x128 tile, BK=64, double-buffered; counted vmcnt(8), raw barriers.
// All operands bf16 via linear-dest gl_lds with pre-swizzled source,
// T2 XOR swizzle (byte ^= (row&7)<<4) on reads.
// MODE 0: -> Qh[b][h][s][dh] bf16 row-major, scale log2e/8, bias[n]
// MODE 1: -> Kf fragment-major (QK A-operand frags), bias[n]
// MODE 2: A=WvT, Bt=vb -> Vf fragment-major (PV B-operand), bias[m]
// MODE 3: -> fp32 [m][n] + bias[n]
template <int MODE>
__global__ __launch_bounds__(256, 2)
void gemm_bt(const u16* __restrict__ A, const u16* __restrict__ Bt,
             const float* __restrict__ bias, void* __restrict__ Out,
             int M, int N, int K) {
  __shared__ u16 Asl[2][128 * 64];
  __shared__ u16 Bsl[2][128 * 64];
  const int ntile = N >> 7;
  int bid = blockIdx.x;
  bid = (bid & 7) * ((int)gridDim.x >> 3) + (bid >> 3);  // XCD chunk swizzle
  int m0 = (bid / ntile) * 128, n0 = (bid % ntile) * 128;
  int tid = threadIdx.x;
  int lane = tid & 63, wv = tid >> 6;
  int wr = wv >> 1, wc = wv & 1;

  auto stage = [&](int buf, int k0) {
#pragma unroll
    for (int it = 0; it < 4; ++it) {
      int c = tid + it * 256;            // 1024 chunks of 16B per matrix
      int row = c >> 3, sl = c & 7;      // 8 x 16B per 128B row
      int ssl = sl ^ (row & 7);          // pre-swizzled source slot
      gl_lds16(A + (size_t)(m0 + row) * K + k0 + ssl * 8,
               (char*)&Asl[buf][0] + c * 16);
      gl_lds16(Bt + (size_t)(n0 + row) * K + k0 + ssl * 8,
               (char*)&Bsl[buf][0] + c * 16);
    }
  };

  f32x4 acc[4][4] = {};
  stage(0, 0);

  int nk = K >> 6;
  for (int kt = 0; kt < nk; ++kt) {
    int buf = kt & 1;
    if (kt + 1 < nk) {
      stage(buf ^ 1, (kt + 1) << 6);
      asm volatile("s_waitcnt vmcnt(8) lgkmcnt(0)" ::: "memory");
    } else {
      asm volatile("s_waitcnt vmcnt(0) lgkmcnt(0)" ::: "memory");
    }
    __builtin_amdgcn_s_barrier();  // cur tile ready in LDS
#pragma unroll
    for (int kk = 0; kk < 2; ++kk) {
      bf16x8 af[4], bfr[4];
#pragma unroll
      for (int i = 0; i < 4; ++i) {
        int ar = wr * 64 + i * 16 + (lane & 15);
        int abyt = (ar * 128 + (kk * 32 + (lane >> 4) * 8) * 2) ^
                   ((ar & 7) << 4);
        af[i] = *(const bf16x8*)((const char*)&Asl[buf][0] + abyt);
        int br = wc * 64 + i * 16 + (lane & 15);
        int bbyt = (br * 128 + (kk * 32 + (lane >> 4) * 8) * 2) ^
                   ((br & 7) << 4);
        bfr[i] = *(const bf16x8*)((const char*)&Bsl[buf][0] + bbyt);
      }
#pragma unroll
      for (int i = 0; i < 4; ++i)
#pragma unroll
        for (int j = 0; j < 4; ++j)
          acc[i][j] = __builtin_amdgcn_mfma_f32_16x16x32_bf16(
              af[i], bfr[j], acc[i][j], 0, 0, 0);
    }
    __builtin_amdgcn_s_barrier();  // all waves done reading cur tile
  }

  int cg = lane >> 4, cc = lane & 15;
#pragma unroll
  for (int i = 0; i < 4; ++i) {
#pragma unroll
    for (int j = 0; j < 4; ++j) {
#pragma unroll
      for (int r = 0; r < 4; ++r) {
        int m = m0 + wr * 64 + i * 16 + cg * 4 + r;
        int n = n0 + wc * 64 + j * 16 + cc;
        float val = acc[i][j][r];
        if (MODE == 0) {
          // fold (1/sqrt(Dh)) * log2(e) into Q for exp2-based softmax
          val = (val + bias[n]) * 0.18033688011112042f;
          int b = m >> 11, s = m & 2047, h = n >> 6, dh = n & 63;
          ((u16*)Out)[((size_t)((b * SH + h) * SS + s) << 6) + dh] = f2bf(val);
        } else if (MODE == 1) {
          // Kf frag-major: frag(kb32=s>>5, st=dh>>4), lane=(s&31)|((dh&8)<<2)
          val += bias[n];
          int b = m >> 11, s = m & 2047, h = n >> 6, dh = n & 63;
          size_t off = ((size_t)(b * SH + h) << 17) + ((size_t)(s >> 5) << 11) +
                       ((size_t)(dh >> 4) << 9) +
                       ((size_t)((s & 31) | ((dh & 8) << 2)) << 3) + (dh & 7);
          ((u16*)Out)[off] = f2bf(val);
        } else if (MODE == 2) {
          // Vf frag-major: frag(kb16=s>>4, dhh=dh>>5), lane=((s>>3)&1)*32+(dh&31)
          val += bias[m];  // m is the 1024-dim here
          int h = m >> 6, dh = m & 63, b = n >> 11, s = n & 2047;
          size_t off = ((size_t)(b * SH + h) << 17) + ((size_t)(s >> 4) << 10) +
                       ((size_t)(dh >> 5) << 9) +
                       ((size_t)(((s >> 3) & 1) * 32 + (dh & 31)) << 3) +
                       (s & 7);
          ((u16*)Out)[off] = f2bf(val);
        } else {
          val += bias[n];
          ((float*)Out)[(size_t)m * N + n] = val;
        }
      }
    }
  }
}

// ---------------- attention (frag-major LDS, ring-4, QK(t) || PV(t-1)) --
// grid 512 = 64 bh x 8 q-tiles of 256 rows; 4 waves x 64 q-rows (u=2).
// Cross-tile software pipeline: each barrier interval runs PV of tile t-1
// (MFMA-heavy, inputs ready) and QK+exp of tile t (fresh chain) in ONE
// scheduling region -> independent chains hide each other's latency.
// Two static pk register sets (rule #20). Counted vmcnt(4), 1 barrier/tile.
__global__ __launch_bounds__(256, 2)
void attn_kernel(const u16* __restrict__ Qh, const u16* __restrict__ Kf,
                 const u16* __restrict__ Vf, const float* __restrict__ lwg,
                 u16* __restrict__ Ctx) {
  __shared__ u16 Kl[4][4096];  // 8KB per 64-key tile (frag-major, linear)
  __shared__ u16 Vl[4][4096];

  int bid = blockIdx.x;
  int swz = (bid & 7) * 64 + (bid >> 3);  // XCD chunk swizzle (512 = 8*64)
  int bh = swz >> 3;                      // 0..63
  int qt = swz & 7;                       // 0..7
  int b = bh >> 4, hh = bh & 15;
  int q0 = qt * 256;
  int tid = threadIdx.x, lane = tid & 63, wv = tid >> 6;
  int ql = lane & 31, h = lane >> 5;
  const size_t basebh = (size_t)bh * (SS * SDH);
  const char* Ksrc = (const char*)(Kf + basebh);
  const char* Vsrc = (const char*)(Vf + basebh);
  const float* lwp = lwg + b * SS;

  // Q fragments (B-operand): q-block u covers cols q0+wv*64+u*32+ql
  bf16x8 qf[2][4];
#pragma unroll
  for (int u = 0; u < 2; ++u) {
    const u16* qp =
        Qh + basebh + (size_t)(q0 + wv * 64 + u * 32 + ql) * SDH + h * 8;
#pragma unroll
    for (int st = 0; st < 4; ++st) qf[u][st] = *(const bf16x8*)(qp + st * 16);
  }

  auto stage = [&](int s, int t) {
#pragma unroll
    for (int it = 0; it < 2; ++it) {
      int c = tid + it * 256;  // 512 chunks of 16B = 8KB, fully linear
      gl_lds16(Ksrc + (size_t)t * 8192 + c * 16, (char*)&Kl[s][0] + c * 16);
      gl_lds16(Vsrc + (size_t)t * 8192 + c * 16, (char*)&Vl[s][0] + c * 16);
    }
  };

  f32x16 ctx[2][2] = {};
  float rs[2] = {0.f, 0.f};
  u32 pkA[2][8][2], pkB[2][8][2];

  // QK^T + exp2 for tile t -> pk set
  auto qk = [&](int t, u32 (&pk)[2][8][2]) {
    const char* Ks = (const char*)&Kl[t & 3][0];
    int kvb = t * 64;
#pragma unroll
    for (int kt = 0; kt < 2; ++kt) {
      bf16x8 kf[4];
#pragma unroll
      for (int st = 0; st < 4; ++st)
        kf[st] = *(const bf16x8*)(Ks + (kt * 4 + st) * 1024 + lane * 16);
      float4 lw[4];
#pragma unroll
      for (int e2 = 0; e2 < 4; ++e2)
        lw[e2] = *(const float4*)(lwp + kvb + kt * 32 + e2 * 8 + h * 4);
#pragma unroll
      for (int u = 0; u < 2; ++u) {
        f32x16 sc;
#pragma unroll
        for (int e2 = 0; e2 < 4; ++e2) {
          sc[e2 * 4 + 0] = lw[e2].x;
          sc[e2 * 4 + 1] = lw[e2].y;
          sc[e2 * 4 + 2] = lw[e2].z;
          sc[e2 * 4 + 3] = lw[e2].w;
        }
        __builtin_amdgcn_s_setprio(1);
#pragma unroll
        for (int st = 0; st < 4; ++st)
          sc = __builtin_amdgcn_mfma_f32_32x32x16_bf16(kf[st], qf[u][st], sc,
                                                       0, 0, 0);
        __builtin_amdgcn_s_setprio(0);
        // lane: P[q=ql][k = kvb + 32kt + (reg&3) + 8*(reg>>2) + 4h]
#pragma unroll
        for (int e2 = 0; e2 < 4; ++e2) {
          float v0 = __builtin_amdgcn_exp2f(sc[e2 * 4 + 0]);
          float v1 = __builtin_amdgcn_exp2f(sc[e2 * 4 + 1]);
          float v2 = __builtin_amdgcn_exp2f(sc[e2 * 4 + 2]);
          float v3 = __builtin_amdgcn_exp2f(sc[e2 * 4 + 3]);
          rs[u] += (v0 + v1) + (v2 + v3);
          u32 p0, p1;
          asm("v_cvt_pk_bf16_f32 %0, %1, %2" : "=v"(p0) : "v"(v0), "v"(v1));
          asm("v_cvt_pk_bf16_f32 %0, %1, %2" : "=v"(p1) : "v"(v2), "v"(v3));
          pk[u][kt * 4 + e2][0] = p0;
          pk[u][kt * 4 + e2][1] = p1;
        }
      }
    }
  };

  // PV for tile t <- pk set (V frags lane-contiguous, conflict-free)
  auto pv = [&](int t, u32 (&pk)[2][8][2]) {
    const char* Vs = (const char*)&Vl[t & 3][0];
#pragma unroll
    for (int ksl = 0; ksl < 4; ++ksl) {
      bf16x8 vf0 = *(const bf16x8*)(Vs + (ksl * 2 + 0) * 1024 + lane * 16);
      bf16x8 vf1 = *(const bf16x8*)(Vs + (ksl * 2 + 1) * 1024 + lane * 16);
#pragma unroll
      for (int u = 0; u < 2; ++u) {
        u32 d0 = pk[u][2 * ksl][0], d1 = pk[u][2 * ksl][1];
        u32 s0 = pk[u][2 * ksl + 1][0], s1 = pk[u][2 * ksl + 1][1];
        asm("v_permlane32_swap_b32 %0, %1" : "+v"(d0), "+v"(s0));
        asm("v_permlane32_swap_b32 %0, %1" : "+v"(d1), "+v"(s1));
        union { u32 uu[4]; bf16x8 v; } pa;
        pa.uu[0] = d0; pa.uu[1] = d1; pa.uu[2] = s0; pa.uu[3] = s1;
        __builtin_amdgcn_s_setprio(1);
        ctx[u][0] = __builtin_amdgcn_mfma_f32_32x32x16_bf16(pa.v, vf0,
                                                            ctx[u][0], 0, 0, 0);
        ctx[u][1] = __builtin_amdgcn_mfma_f32_32x32x16_bf16(pa.v, vf1,
                                                            ctx[u][1], 0, 0, 0);
        __builtin_amdgcn_s_setprio(0);
      }
    }
  };

  stage(0, 0);
  stage(1, 1);

  // interval 0: QK(0) only
  asm volatile("s_waitcnt vmcnt(4)" ::: "memory");
  __builtin_amdgcn_s_barrier();
  stage(2, 2);
  qk(0, pkA);

  // intervals 1..30 (pairs): PV(t-1) || QK(t)
  for (int t = 1; t < 30; t += 2) {
    asm volatile("s_waitcnt vmcnt(4)" ::: "memory");
    __builtin_amdgcn_s_barrier();
    stage((t + 2) & 3, t + 2);
    pv(t - 1, pkA);
    qk(t, pkB);

    asm volatile("s_waitcnt vmcnt(4)" ::: "memory");
    __builtin_amdgcn_s_barrier();
    if (t + 3 < 32) stage((t + 3) & 3, t + 3);
    pv(t, pkB);
    qk(t + 1, pkA);
  }

  // tail: interval 31 + final PV(31)
  asm volatile("s_waitcnt vmcnt(0)" ::: "memory");
  __builtin_amdgcn_s_barrier();
  pv(30, pkA);
  qk(31, pkB);
  pv(31, pkB);

  // denominator + context write
#pragma unroll
  for (int u = 0; u < 2; ++u) {
    float rsu = rs[u];
    rsu += __shfl_xor(rsu, 32, 64);
    float rinv = 1.0f / (rsu + 1e-12f);
#pragma unroll
    for (int reg = 0; reg < 16; ++reg) {
      int qrow = (reg & 3) + 8 * (reg >> 2) + 4 * h;
      float ri = __shfl(rinv, qrow, 64);
      int srow = q0 + wv * 64 + u * 32 + qrow;
      size_t base = ((size_t)(b * SS + srow) << 10) + hh * SDH;
      Ctx[base + ql] = f2bf(ctx[u][0][reg] * ri);
      Ctx[base + 32 + ql] = f2bf(ctx[u][1][reg] * ri);
    }
  }
}

extern "C" void kernel_launch(void* const* d_in, const int* in_sizes, int n_in,
                              void* d_out, int out_size, void* d_ws,
                              size_t ws_size, hipStream_t stream) {
  const float* q = (const float*)d_in[0];
  const float* k = (const float*)d_in[1];
  const float* v = (const float*)d_in[2];
  const float* w = (const float*)d_in[3];
  const float* Wq = (const float*)d_in[4];
  const float* bq = (const float*)d_in[5];
  const float* Wk = (const float*)d_in[6];
  const float* bk = (const float*)d_in[7];
  const float* Wv = (const float*)d_in[8];
  const float* bv = (const float*)d_in[9];
  const float* Wo = (const float*)d_in[10];
  const float* bo = (const float*)d_in[11];
  float* out = (float*)d_out;

  char* ws = (char*)d_ws;
  const size_t SZ = (size_t)8192 * 1024 * 2;  // one bf16 [8192][1024] buffer
  u16* qb = (u16*)(ws);
  u16* kb = (u16*)(ws + SZ);
  u16* vb = (u16*)(ws + 2 * SZ);
  u16* WqT = (u16*)(ws + 3 * SZ);
  u16* WkT = WqT + 1024 * 1024;
  u16* WvT = WkT + 1024 * 1024;
  u16* WoT = WvT + 1024 * 1024;
  u16* Qh = (u16*)(ws + 3 * SZ + (size_t)4 * 1024 * 1024 * 2);
  u16* Kf = Qh + (size_t)8192 * 1024;
  u16* Vf = Kf + (size_t)8192 * 1024;
  float* lwg = (float*)(ws + 3 * SZ + (size_t)4 * 1024 * 1024 * 2 +
                        (size_t)3 * 8192 * 1024 * 2);
  u16* Ctx = qb;  // qb is dead after the Q projection

  // 1) casts + tiny precomputes
  cast_bf16_kernel<<<4096, 256, 0, stream>>>(q, (u32*)qb, 1048576);
  cast_bf16_kernel<<<4096, 256, 0, stream>>>(k, (u32*)kb, 1048576);
  cast_bf16_kernel<<<4096, 256, 0, stream>>>(v, (u32*)vb, 1048576);
  log2w_kernel<<<32, 256, 0, stream>>>(w, lwg);
  dim3 tb(32, 8), tg(32, 32, 4);
  transpose_cast_kernel<<<tg, tb, 0, stream>>>(Wq, Wk, Wv, Wo,
                                               WqT, WkT, WvT, WoT);

  // 2) projections (all-bf16 staging)
  gemm_bt<0><<<512, 256, 0, stream>>>(qb, WqT, bq, Qh, 8192, 1024, 1024);
  gemm_bt<1><<<512, 256, 0, stream>>>(kb, WkT, bk, Kf, 8192, 1024, 1024);
  gemm_bt<2><<<512, 256, 0, stream>>>(WvT, vb, bv, Vf, 1024, 8192, 1024);

  // 3) attention
  attn_kernel<<<512, 256, 0, stream>>>(Qh, Kf, Vf, lwg, Ctx);

  // 4) output projection (fp32 out + bias)
  gemm_bt<3><<<512, 256, 0, stream>>>(Ctx, WoT, bo, out, 8192, 1024, 1024);
}